// Round 5
// baseline (265.250 us; speedup 1.0000x reference)
//
#include <hip/hip_runtime.h>
#include <hip/hip_cooperative_groups.h>
#include <math.h>

namespace cg = cooperative_groups;

// Problem constants (fixed by the reference)
#define BG 64            // graphs
#define NN 2048          // nodes per graph
#define HH 64            // hidden dim
#define NHD 4            // heads
#define DHD 16           // head dim
#define MM (3*NN)        // 6144 framelet rows
#define EE (8*MM)        // 49152 nnz per graph
#define SLICES 8         // E-slices per graph (phase A)
#define EPB (EE/SLICES)  // 6144 entries per phase-A block
#define KS 8             // K-split blocks per graph (phase B)
#define NPB (NN/KS)      // 256 nodes per phase-B block

// One cooperative kernel, 512 blocks x 256 threads, 3 phases with grid syncs.
// LDS is a union over phases; max 52 KB -> 3 blocks/CU -> 768 >= 512 co-resident.
__global__ __launch_bounds__(256) void fused_kernel(
        const float* __restrict__ x,
        const int* __restrict__ d_rows, const int* __restrict__ d_cols,
        const float* __restrict__ d_vals, const int* __restrict__ d_index,
        const float* __restrict__ Wq, const float* __restrict__ Wk,
        const float* __restrict__ Wv, float* __restrict__ out,
        float* __restrict__ part_wsum, float* __restrict__ part_pool) {
    __shared__ union SM {
        struct { float w[3 * NN]; int gidx[MM]; } a;                   // 48 KB
        struct { float wred[3 * NPB]; float red[4][3][HH]; } b;        // 6 KB
        struct { float p[3][HH]; float Wl[3][HH][HH + 1];
                 float Ql[3][HH]; float Kl[3][HH]; float Vl[3][HH]; } c; // ~52 KB
    } sm;

    cg::grid_group grid = cg::this_grid();
    const int tid = threadIdx.x;

    // ---------------- Phase A: slice-partial wsum via LDS scatter ----------
    {
        const int b = blockIdx.x / SLICES;
        const int s = blockIdx.x % SLICES;

        const int4* di4 = (const int4*)(d_index + (size_t)b * MM);
        for (int i = tid; i < MM / 4; i += 256) ((int4*)sm.a.gidx)[i] = di4[i];
        for (int i = tid; i < 3 * NN; i += 256) sm.a.w[i] = 0.0f;
        __syncthreads();

        const size_t base = (size_t)b * EE + (size_t)s * EPB;   // 16B-aligned
        const int4*   rows4 = (const int4*)(d_rows + base);
        const int4*   cols4 = (const int4*)(d_cols + base);
        const float4* vals4 = (const float4*)(d_vals + base);

#pragma unroll
        for (int it = 0; it < EPB / 4 / 256; ++it) {   // 6 iterations
            const int idx = it * 256 + tid;
            int4   r = rows4[idx];
            int4   c = cols4[idx];
            float4 v = vals4[idx];
            int g0 = sm.a.gidx[r.x], g1 = sm.a.gidx[r.y];
            int g2 = sm.a.gidx[r.z], g3 = sm.a.gidx[r.w];
            atomicAdd(&sm.a.w[g0 * NN + c.x], v.x);
            atomicAdd(&sm.a.w[g1 * NN + c.y], v.y);
            atomicAdd(&sm.a.w[g2 * NN + c.z], v.z);
            atomicAdd(&sm.a.w[g3 * NN + c.w], v.w);
        }
        __syncthreads();

        float* outp = part_wsum + ((size_t)b * SLICES + s) * (3 * NN);
        for (int i = tid; i < 3 * NN; i += 256) outp[i] = sm.a.w[i];
    }

    grid.sync();

    // ---------------- Phase B: part_pool[b][ks][g][h] = wred @ x-slice -----
    {
        const int b  = blockIdx.x / KS;
        const int ks = blockIdx.x % KS;

        for (int i = tid; i < 3 * NPB; i += 256) {
            const int g = i / NPB, n = i % NPB;
            const float* src = part_wsum + (size_t)b * SLICES * (3 * NN)
                             + (size_t)g * NN + (size_t)ks * NPB + n;
            float v = 0.0f;
#pragma unroll
            for (int s = 0; s < SLICES; ++s) v += src[(size_t)s * (3 * NN)];
            sm.b.wred[i] = v;
        }
        __syncthreads();

        const int w = tid >> 6, h = tid & 63;
        const float* xb = x + ((size_t)b * NN + (size_t)ks * NPB) * HH + h;
        float a0 = 0.0f, a1 = 0.0f, a2 = 0.0f;
#pragma unroll 4
        for (int n = w; n < NPB; n += 4) {             // 64 iters/thread
            const float xv = xb[(size_t)n * HH];
            a0 += sm.b.wred[0 * NPB + n] * xv;         // wave-uniform broadcast
            a1 += sm.b.wred[1 * NPB + n] * xv;
            a2 += sm.b.wred[2 * NPB + n] * xv;
        }
        sm.b.red[w][0][h] = a0; sm.b.red[w][1][h] = a1; sm.b.red[w][2][h] = a2;
        __syncthreads();

        if (tid < 3 * HH) {
            const int g = tid >> 6, h2 = tid & 63;
            const float v = sm.b.red[0][g][h2] + sm.b.red[1][g][h2]
                          + sm.b.red[2][g][h2] + sm.b.red[3][g][h2];
            part_pool[(((size_t)b * KS + ks) * 3 + g) * HH + h2] = v;
        }
    }

    grid.sync();

    // ---------------- Phase C: tiny 3-token attention (blocks 0..63) -------
    if (blockIdx.x < BG) {
        const int b = blockIdx.x;
        const int q = tid >> 6, h = tid & 63;          // valid for tid < 192

        if (tid < 192) {
            float pv = 0.0f;
#pragma unroll
            for (int s = 0; s < KS; ++s)
                pv += part_pool[(((size_t)b * KS + s) * 3 + q) * HH + h];
            sm.c.p[q][h] = pv;
        }
        for (int i = tid; i < 3 * HH * HH; i += 256) {
            const int m = i >> 12;                     // 4096 elems per matrix
            const int rem = i & 4095;
            const int r = rem >> 6, c2 = rem & 63;
            const float* Wsrc = (m == 0) ? Wq : (m == 1) ? Wk : Wv;
            sm.c.Wl[m][r][c2] = Wsrc[rem];
        }
        __syncthreads();

        if (tid < 192) {
            float accq = 0.0f, acck = 0.0f, accv = 0.0f;
#pragma unroll
            for (int k = 0; k < HH; ++k) {
                const float pk = sm.c.p[q][k];
                accq += pk * sm.c.Wl[0][h][k];
                acck += pk * sm.c.Wl[1][h][k];
                accv += pk * sm.c.Wl[2][h][k];
            }
            sm.c.Ql[q][h] = accq; sm.c.Kl[q][h] = acck; sm.c.Vl[q][h] = accv;
        }
        __syncthreads();

        if (tid < 192) {
            const int nh = h >> 4;
            float s0 = 0.0f, s1 = 0.0f, s2 = 0.0f;
#pragma unroll
            for (int d = 0; d < DHD; ++d) {
                const float qq = sm.c.Ql[q][nh * DHD + d];
                s0 += qq * sm.c.Kl[0][nh * DHD + d];
                s1 += qq * sm.c.Kl[1][nh * DHD + d];
                s2 += qq * sm.c.Kl[2][nh * DHD + d];
            }
            s0 *= 0.25f; s1 *= 0.25f; s2 *= 0.25f;
            const float mx = fmaxf(s0, fmaxf(s1, s2));
            const float e0 = expf(s0 - mx), e1 = expf(s1 - mx), e2 = expf(s2 - mx);
            const float inv = 1.0f / (e0 + e1 + e2);
            const float av = (e0 * sm.c.Vl[0][h] + e1 * sm.c.Vl[1][h]
                            + e2 * sm.c.Vl[2][h]) * inv;
            out[(size_t)b * (3 * HH) + (size_t)q * HH + h] = av;
        }
    }
}

extern "C" void kernel_launch(void* const* d_in, const int* in_sizes, int n_in,
                              void* d_out, int out_size, void* d_ws, size_t ws_size,
                              hipStream_t stream) {
    const float* x      = (const float*)d_in[0];
    // d_in[1] = batch (unused; fixed N nodes/graph), d_in[2] = batch_size (fixed 64)
    const int*   d_rows = (const int*)d_in[3];
    const int*   d_cols = (const int*)d_in[4];
    const float* d_vals = (const float*)d_in[5];
    const int*   d_index= (const int*)d_in[6];
    const float* Wq     = (const float*)d_in[7];
    const float* Wk     = (const float*)d_in[8];
    const float* Wv     = (const float*)d_in[9];
    float* out = (float*)d_out;

    // workspace layout (all fully written before read; no zeroing needed):
    //   part_wsum: B*SLICES*3*N floats = 12.58 MB
    //   part_pool: B*KS*3*H floats     = 0.39 MB
    float* part_wsum = (float*)d_ws;
    float* part_pool = part_wsum + (size_t)BG * SLICES * 3 * NN;

    void* args[] = { (void*)&x, (void*)&d_rows, (void*)&d_cols, (void*)&d_vals,
                     (void*)&d_index, (void*)&Wq, (void*)&Wk, (void*)&Wv,
                     (void*)&out, (void*)&part_wsum, (void*)&part_pool };
    hipLaunchCooperativeKernel((void*)fused_kernel, dim3(BG * SLICES),
                               dim3(256), args, 0, stream);
}

// Round 6
// 180.325 us; speedup vs baseline: 1.4710x; 1.4710x over previous
//
#include <hip/hip_runtime.h>
#include <math.h>

// Problem constants (fixed by the reference)
#define BG 64            // graphs
#define NN 2048          // nodes per graph
#define HH 64            // hidden dim
#define NHD 4            // heads
#define DHD 16           // head dim
#define MM (3*NN)        // 6144 framelet rows
#define EE (8*MM)        // 49152 nnz per graph
#define SLICES 4         // E-slices per graph (pass A)
#define EPB (EE/SLICES)  // 12288 entries per pass-A block
#define KS 8             // node-split blocks per graph (pass B)
#define NPB (NN/KS)      // 256 nodes per pass-B block

// ---------------- Pass A: slice-partial wsum via LDS scatter ----------------
// 256 blocks x 512 threads. d_index staged in LDS (coalesced) so the
// row->group gather is a near-free LDS read. Also zeroes the per-graph
// completion counters used by pass BC (safe: stream-ordered before BC).
__global__ __launch_bounds__(512) void passA_kernel(
        const int* __restrict__ d_rows, const int* __restrict__ d_cols,
        const float* __restrict__ d_vals, const int* __restrict__ d_index,
        float* __restrict__ part_wsum, int* __restrict__ counters) {
    __shared__ float w[3 * NN];                    // 24 KB
    __shared__ int   gidx[MM];                     // 24 KB (row -> group)
    const int b = blockIdx.x / SLICES;
    const int s = blockIdx.x % SLICES;
    const int tid = threadIdx.x;

    if (s == 0 && tid == 0) counters[b] = 0;

    const int4* di4 = (const int4*)(d_index + (size_t)b * MM);
    for (int i = tid; i < MM / 4; i += 512) ((int4*)gidx)[i] = di4[i];
    for (int i = tid; i < 3 * NN; i += 512) w[i] = 0.0f;
    __syncthreads();

    const size_t base = (size_t)b * EE + (size_t)s * EPB;   // 16B-aligned
    const int4*   rows4 = (const int4*)(d_rows + base);
    const int4*   cols4 = (const int4*)(d_cols + base);
    const float4* vals4 = (const float4*)(d_vals + base);

#pragma unroll
    for (int it = 0; it < EPB / 4 / 512; ++it) {   // 6 iterations
        const int idx = it * 512 + tid;
        int4   r = rows4[idx];
        int4   c = cols4[idx];
        float4 v = vals4[idx];
        int g0 = gidx[r.x], g1 = gidx[r.y], g2 = gidx[r.z], g3 = gidx[r.w];
        atomicAdd(&w[g0 * NN + c.x], v.x);
        atomicAdd(&w[g1 * NN + c.y], v.y);
        atomicAdd(&w[g2 * NN + c.z], v.z);
        atomicAdd(&w[g3 * NN + c.w], v.w);
    }
    __syncthreads();

    float* out = part_wsum + ((size_t)b * SLICES + s) * (3 * NN);
    for (int i = tid; i < 3 * NN; i += 512) out[i] = w[i];
}

// ---------------- Pass BC: pool GEMV + (last block per graph) attention -----
// 512 blocks x 256 threads. Phase B: reduce slice partials, wred @ x-slice.
// The last-finishing block of each graph (device-scope counter) runs the tiny
// 3-token attention for that graph — removes the separate pass-C dispatch.
__global__ __launch_bounds__(256) void passBC_kernel(
        const float* __restrict__ x, const float* __restrict__ part_wsum,
        float* __restrict__ part_pool, int* __restrict__ counters,
        const float* __restrict__ Wq, const float* __restrict__ Wk,
        const float* __restrict__ Wv, float* __restrict__ out) {
    __shared__ union SM {
        struct { float wred[3 * NPB]; float red[4][3][HH]; } b;        // 6 KB
        struct { float p[3][HH]; float Wl[3][HH][HH + 1];
                 float Ql[3][HH]; float Kl[3][HH]; float Vl[3][HH]; } c; // ~52 KB
    } sm;
    __shared__ int isLast;
    const int b  = blockIdx.x / KS;
    const int ks = blockIdx.x % KS;
    const int tid = threadIdx.x;                   // 256 threads

    // ---- Phase B ----
    for (int i = tid; i < 3 * NPB; i += 256) {
        const int g = i / NPB, n = i % NPB;
        const float* src = part_wsum + (size_t)b * SLICES * (3 * NN)
                         + (size_t)g * NN + (size_t)ks * NPB + n;
        float v = 0.0f;
#pragma unroll
        for (int s = 0; s < SLICES; ++s) v += src[(size_t)s * (3 * NN)];
        sm.b.wred[i] = v;
    }
    __syncthreads();

    const int w = tid >> 6, h = tid & 63;
    const float* xb = x + ((size_t)b * NN + (size_t)ks * NPB) * HH + h;
    float a0 = 0.0f, a1 = 0.0f, a2 = 0.0f;
#pragma unroll 4
    for (int n = w; n < NPB; n += 4) {             // 64 iters/thread
        const float xv = xb[(size_t)n * HH];
        a0 += sm.b.wred[0 * NPB + n] * xv;         // wave-uniform broadcast
        a1 += sm.b.wred[1 * NPB + n] * xv;
        a2 += sm.b.wred[2 * NPB + n] * xv;
    }
    sm.b.red[w][0][h] = a0; sm.b.red[w][1][h] = a1; sm.b.red[w][2][h] = a2;
    __syncthreads();

    if (tid < 3 * HH) {
        const int g = tid >> 6, h2 = tid & 63;
        const float v = sm.b.red[0][g][h2] + sm.b.red[1][g][h2]
                      + sm.b.red[2][g][h2] + sm.b.red[3][g][h2];
        part_pool[(((size_t)b * KS + ks) * 3 + g) * HH + h2] = v;
    }
    __syncthreads();                               // all B writes issued

    if (tid == 0) {
        __threadfence();                           // release part_pool writes
        const int old = atomicAdd(&counters[b], 1);
        isLast = (old == KS - 1) ? 1 : 0;
    }
    __syncthreads();
    if (!isLast) return;

    // ---- Phase C (one block per graph) ----
    __threadfence();                               // acquire others' writes
    const int q = tid >> 6;                        // valid for tid < 192

    if (tid < 192) {
        float pv = 0.0f;
#pragma unroll
        for (int s = 0; s < KS; ++s)
            pv += part_pool[(((size_t)b * KS + s) * 3 + q) * HH + h];
        sm.c.p[q][h] = pv;
    }
    for (int i = tid; i < 3 * HH * HH; i += 256) {
        const int m = i >> 12;                     // 4096 elems per matrix
        const int rem = i & 4095;
        const int r = rem >> 6, c2 = rem & 63;
        const float* Wsrc = (m == 0) ? Wq : (m == 1) ? Wk : Wv;
        sm.c.Wl[m][r][c2] = Wsrc[rem];
    }
    __syncthreads();

    if (tid < 192) {
        float accq = 0.0f, acck = 0.0f, accv = 0.0f;
#pragma unroll
        for (int k = 0; k < HH; ++k) {
            const float pk = sm.c.p[q][k];
            accq += pk * sm.c.Wl[0][h][k];
            acck += pk * sm.c.Wl[1][h][k];
            accv += pk * sm.c.Wl[2][h][k];
        }
        sm.c.Ql[q][h] = accq; sm.c.Kl[q][h] = acck; sm.c.Vl[q][h] = accv;
    }
    __syncthreads();

    if (tid < 192) {
        const int nh = h >> 4;
        float s0 = 0.0f, s1 = 0.0f, s2 = 0.0f;
#pragma unroll
        for (int d = 0; d < DHD; ++d) {
            const float qq = sm.c.Ql[q][nh * DHD + d];
            s0 += qq * sm.c.Kl[0][nh * DHD + d];
            s1 += qq * sm.c.Kl[1][nh * DHD + d];
            s2 += qq * sm.c.Kl[2][nh * DHD + d];
        }
        s0 *= 0.25f; s1 *= 0.25f; s2 *= 0.25f;
        const float mx = fmaxf(s0, fmaxf(s1, s2));
        const float e0 = expf(s0 - mx), e1 = expf(s1 - mx), e2 = expf(s2 - mx);
        const float inv = 1.0f / (e0 + e1 + e2);
        const float av = (e0 * sm.c.Vl[0][h] + e1 * sm.c.Vl[1][h]
                        + e2 * sm.c.Vl[2][h]) * inv;
        out[(size_t)b * (3 * HH) + (size_t)q * HH + h] = av;
    }
}

extern "C" void kernel_launch(void* const* d_in, const int* in_sizes, int n_in,
                              void* d_out, int out_size, void* d_ws, size_t ws_size,
                              hipStream_t stream) {
    const float* x      = (const float*)d_in[0];
    // d_in[1] = batch (unused; fixed N nodes/graph), d_in[2] = batch_size (fixed 64)
    const int*   d_rows = (const int*)d_in[3];
    const int*   d_cols = (const int*)d_in[4];
    const float* d_vals = (const float*)d_in[5];
    const int*   d_index= (const int*)d_in[6];
    const float* Wq     = (const float*)d_in[7];
    const float* Wk     = (const float*)d_in[8];
    const float* Wv     = (const float*)d_in[9];
    float* out = (float*)d_out;

    // workspace layout (all fully written before read; counters zeroed by A):
    //   part_wsum: B*SLICES*3*N floats = 6.29 MB
    //   part_pool: B*KS*3*H floats     = 0.39 MB
    //   counters : B ints
    float* part_wsum = (float*)d_ws;
    float* part_pool = part_wsum + (size_t)BG * SLICES * 3 * NN;
    int*   counters  = (int*)(part_pool + (size_t)BG * KS * 3 * HH);

    passA_kernel<<<BG * SLICES, 512, 0, stream>>>(d_rows, d_cols, d_vals,
                                                  d_index, part_wsum, counters);
    passBC_kernel<<<BG * KS, 256, 0, stream>>>(x, part_wsum, part_pool,
                                               counters, Wq, Wk, Wv, out);
}

// Round 7
// 142.312 us; speedup vs baseline: 1.8639x; 1.2671x over previous
//
#include <hip/hip_runtime.h>
#include <math.h>

// Problem constants (fixed by the reference)
#define BG 64            // graphs
#define NN 2048          // nodes per graph
#define HH 64            // hidden dim
#define NHD 4            // heads
#define DHD 16           // head dim
#define MM (3*NN)        // 6144 framelet rows
#define EE (8*MM)        // 49152 nnz per graph
#define SLICES 4         // E-slices per graph (pass A)
#define EPB (EE/SLICES)  // 12288 entries per pass-A block
#define KS 8             // node-split blocks per graph (pass B)
#define NPB (NN/KS)      // 256 nodes per pass-B block

// ---------------- Pass A: wsum[b][g][n] = sum of vals with col n, group g ----
// 256 blocks x 512 threads (48 KB LDS -> 1 block/CU, 8 waves/CU). d_index is
// staged in LDS (coalesced int4) so the row->group gather is a near-free LDS
// read instead of a 64-way-divergent L1 gather. No device-scope sync anywhere.
__global__ __launch_bounds__(512) void passA_kernel(
        const int* __restrict__ d_rows, const int* __restrict__ d_cols,
        const float* __restrict__ d_vals, const int* __restrict__ d_index,
        float* __restrict__ part_wsum) {
    __shared__ float w[3 * NN];                    // 24 KB
    __shared__ int   gidx[MM];                     // 24 KB (row -> group)
    const int b = blockIdx.x / SLICES;
    const int s = blockIdx.x % SLICES;
    const int tid = threadIdx.x;

    const int4* di4 = (const int4*)(d_index + (size_t)b * MM);
    for (int i = tid; i < MM / 4; i += 512) ((int4*)gidx)[i] = di4[i];
    for (int i = tid; i < 3 * NN; i += 512) w[i] = 0.0f;
    __syncthreads();

    const size_t base = (size_t)b * EE + (size_t)s * EPB;   // 16B-aligned
    const int4*   rows4 = (const int4*)(d_rows + base);
    const int4*   cols4 = (const int4*)(d_cols + base);
    const float4* vals4 = (const float4*)(d_vals + base);

#pragma unroll
    for (int it = 0; it < EPB / 4 / 512; ++it) {   // 6 iterations
        const int idx = it * 512 + tid;
        int4   r = rows4[idx];
        int4   c = cols4[idx];
        float4 v = vals4[idx];
        int g0 = gidx[r.x], g1 = gidx[r.y], g2 = gidx[r.z], g3 = gidx[r.w];
        atomicAdd(&w[g0 * NN + c.x], v.x);
        atomicAdd(&w[g1 * NN + c.y], v.y);
        atomicAdd(&w[g2 * NN + c.z], v.z);
        atomicAdd(&w[g3 * NN + c.w], v.w);
    }
    __syncthreads();

    float* out = part_wsum + ((size_t)b * SLICES + s) * (3 * NN);
    for (int i = tid; i < 3 * NN; i += 512) out[i] = w[i];
}

// ---------------- Pass B: part_pool[b][ks][g][h] = wred[g][n] @ x[b][n][h] --
// 512 blocks x 256 threads (4 waves). Each thread keeps all 3 group
// accumulators (3 FMA per x-load); nodes strided across waves; wred[] reads
// are wave-uniform broadcasts (free). Cross-wave LDS reduce at the end.
__global__ __launch_bounds__(256) void passB_kernel(
        const float* __restrict__ x, const float* __restrict__ part_wsum,
        float* __restrict__ part_pool) {
    __shared__ float wred[3 * NPB];                // 3 KB
    __shared__ float red[4][3][HH];                // 3 KB
    const int b  = blockIdx.x / KS;
    const int ks = blockIdx.x % KS;
    const int tid = threadIdx.x;                   // 256 threads

    // reduce slice partials for this node range: wred[g][n]
    for (int i = tid; i < 3 * NPB; i += 256) {
        const int g = i / NPB, n = i % NPB;
        const float* src = part_wsum + (size_t)b * SLICES * (3 * NN)
                         + (size_t)g * NN + (size_t)ks * NPB + n;
        float v = 0.0f;
#pragma unroll
        for (int s = 0; s < SLICES; ++s) v += src[(size_t)s * (3 * NN)];
        wred[i] = v;
    }
    __syncthreads();

    const int w = tid >> 6, h = tid & 63;
    const float* xb = x + ((size_t)b * NN + (size_t)ks * NPB) * HH + h;
    float a0 = 0.0f, a1 = 0.0f, a2 = 0.0f;
#pragma unroll 4
    for (int n = w; n < NPB; n += 4) {             // 64 iters/thread
        const float xv = xb[(size_t)n * HH];
        a0 += wred[0 * NPB + n] * xv;              // wave-uniform broadcast
        a1 += wred[1 * NPB + n] * xv;
        a2 += wred[2 * NPB + n] * xv;
    }
    red[w][0][h] = a0; red[w][1][h] = a1; red[w][2][h] = a2;
    __syncthreads();

    if (tid < 3 * HH) {
        const int g = tid >> 6, h2 = tid & 63;
        const float v = red[0][g][h2] + red[1][g][h2]
                      + red[2][g][h2] + red[3][g][h2];
        part_pool[(((size_t)b * KS + ks) * 3 + g) * HH + h2] = v;
    }
}

// ---------------- Pass C: tiny 3-token multi-head attention per graph -------
__global__ __launch_bounds__(192) void passC_kernel(
        const float* __restrict__ part_pool,
        const float* __restrict__ Wq, const float* __restrict__ Wk,
        const float* __restrict__ Wv, float* __restrict__ out) {
    __shared__ float p[3][HH];                     // pooled [3][64]
    __shared__ float Wl[3][HH][HH + 1];            // padded
    __shared__ float Ql[3][HH], Kl[3][HH], Vl[3][HH];
    const int b = blockIdx.x;
    const int tid = threadIdx.x;                   // 192
    const int q = tid >> 6, h = tid & 63;

    // reduce pool partials
    float pv = 0.0f;
#pragma unroll
    for (int s = 0; s < KS; ++s)
        pv += part_pool[(((size_t)b * KS + s) * 3 + q) * HH + h];
    p[q][h] = pv;

    // stage the three weight matrices (row-major [h][k], padded)
    for (int i = tid; i < 3 * HH * HH; i += 192) {
        const int m = i >> 12;                     // 4096 elems per matrix
        const int rem = i & 4095;
        const int r = rem >> 6, c = rem & 63;
        const float* Wsrc = (m == 0) ? Wq : (m == 1) ? Wk : Wv;
        Wl[m][r][c] = Wsrc[rem];
    }
    __syncthreads();

    // Q[q][h] = sum_k p[q][k] * W[h][k]   (y = x @ W^T)
    float accq = 0.0f, acck = 0.0f, accv = 0.0f;
#pragma unroll
    for (int k = 0; k < HH; ++k) {
        const float pk = p[q][k];
        accq += pk * Wl[0][h][k];
        acck += pk * Wl[1][h][k];
        accv += pk * Wl[2][h][k];
    }
    Ql[q][h] = accq; Kl[q][h] = acck; Vl[q][h] = accv;
    __syncthreads();

    // scores over 3 keys for this (q, head) ; NORM = 1/sqrt(16) = 0.25
    const int nh = h >> 4;
    float s0 = 0.0f, s1 = 0.0f, s2 = 0.0f;
#pragma unroll
    for (int d = 0; d < DHD; ++d) {
        const float qq = Ql[q][nh * DHD + d];
        s0 += qq * Kl[0][nh * DHD + d];
        s1 += qq * Kl[1][nh * DHD + d];
        s2 += qq * Kl[2][nh * DHD + d];
    }
    s0 *= 0.25f; s1 *= 0.25f; s2 *= 0.25f;
    const float mx = fmaxf(s0, fmaxf(s1, s2));
    const float e0 = expf(s0 - mx), e1 = expf(s1 - mx), e2 = expf(s2 - mx);
    const float inv = 1.0f / (e0 + e1 + e2);
    const float av = (e0 * Vl[0][h] + e1 * Vl[1][h] + e2 * Vl[2][h]) * inv;

    out[(size_t)b * (3 * HH) + (size_t)q * HH + h] = av;
}

extern "C" void kernel_launch(void* const* d_in, const int* in_sizes, int n_in,
                              void* d_out, int out_size, void* d_ws, size_t ws_size,
                              hipStream_t stream) {
    const float* x      = (const float*)d_in[0];
    // d_in[1] = batch (unused; fixed N nodes/graph), d_in[2] = batch_size (fixed 64)
    const int*   d_rows = (const int*)d_in[3];
    const int*   d_cols = (const int*)d_in[4];
    const float* d_vals = (const float*)d_in[5];
    const int*   d_index= (const int*)d_in[6];
    const float* Wq     = (const float*)d_in[7];
    const float* Wk     = (const float*)d_in[8];
    const float* Wv     = (const float*)d_in[9];
    float* out = (float*)d_out;

    // workspace layout (all fully written before read; no zeroing needed):
    //   part_wsum: B*SLICES*3*N floats = 6.29 MB
    //   part_pool: B*KS*3*H floats     = 0.39 MB
    float* part_wsum = (float*)d_ws;
    float* part_pool = part_wsum + (size_t)BG * SLICES * 3 * NN;

    passA_kernel<<<BG * SLICES, 512, 0, stream>>>(d_rows, d_cols, d_vals,
                                                  d_index, part_wsum);
    passB_kernel<<<BG * KS, 256, 0, stream>>>(x, part_wsum, part_pool);
    passC_kernel<<<BG, 192, 0, stream>>>(part_pool, Wq, Wk, Wv, out);
}

// Round 8
// 135.853 us; speedup vs baseline: 1.9525x; 1.0475x over previous
//
#include <hip/hip_runtime.h>
#include <math.h>

// Problem constants (fixed by the reference)
#define BG 64            // graphs
#define NN 2048          // nodes per graph
#define HH 64            // hidden dim
#define NHD 4            // heads
#define DHD 16           // head dim
#define MM (3*NN)        // 6144 framelet rows
#define EE (8*MM)        // 49152 nnz per graph
#define SLICES 4         // E-slices per graph (pass A)
#define EPB (EE/SLICES)  // 12288 entries per pass-A block
#define KS 16            // node-split blocks per graph (pass B)
#define NPB (NN/KS)      // 128 nodes per pass-B block

// ---------------- Pass A: wsum[b][g][n] = sum of vals with col n, group g ----
// 256 blocks x 512 threads (48 KB LDS -> 1 block/CU, 8 waves/CU). d_index is
// staged in LDS (coalesced int4) so the row->group gather is a near-free LDS
// read. No device-scope sync anywhere.
__global__ __launch_bounds__(512) void passA_kernel(
        const int* __restrict__ d_rows, const int* __restrict__ d_cols,
        const float* __restrict__ d_vals, const int* __restrict__ d_index,
        float* __restrict__ part_wsum) {
    __shared__ float w[3 * NN];                    // 24 KB
    __shared__ int   gidx[MM];                     // 24 KB (row -> group)
    const int b = blockIdx.x / SLICES;
    const int s = blockIdx.x % SLICES;
    const int tid = threadIdx.x;

    const int4* di4 = (const int4*)(d_index + (size_t)b * MM);
    for (int i = tid; i < MM / 4; i += 512) ((int4*)gidx)[i] = di4[i];
    float4* w4 = (float4*)w;
    const float4 z4 = make_float4(0.f, 0.f, 0.f, 0.f);
    for (int i = tid; i < 3 * NN / 4; i += 512) w4[i] = z4;
    __syncthreads();

    const size_t base = (size_t)b * EE + (size_t)s * EPB;   // 16B-aligned
    const int4*   rows4 = (const int4*)(d_rows + base);
    const int4*   cols4 = (const int4*)(d_cols + base);
    const float4* vals4 = (const float4*)(d_vals + base);

#pragma unroll
    for (int it = 0; it < EPB / 4 / 512; ++it) {   // 6 iterations
        const int idx = it * 512 + tid;
        int4   r = rows4[idx];
        int4   c = cols4[idx];
        float4 v = vals4[idx];
        int g0 = gidx[r.x], g1 = gidx[r.y], g2 = gidx[r.z], g3 = gidx[r.w];
        atomicAdd(&w[g0 * NN + c.x], v.x);
        atomicAdd(&w[g1 * NN + c.y], v.y);
        atomicAdd(&w[g2 * NN + c.z], v.z);
        atomicAdd(&w[g3 * NN + c.w], v.w);
    }
    __syncthreads();

    float4* out4 = (float4*)(part_wsum + ((size_t)b * SLICES + s) * (3 * NN));
    for (int i = tid; i < 3 * NN / 4; i += 512) out4[i] = w4[i];
}

// ---------------- Pass B: part_pool[b][ks][g][h] = wred[g][n] @ x[b][n][h] --
// 1024 blocks x 256 threads (4 blocks/CU -> 16 waves/CU). Each lane loads a
// float4 of x (wave covers 4 rows = 1 KB per load instruction); per-thread
// acc[3 groups][4 h]; row-group reduce via shfl_xor(16/32); cross-wave LDS
// reduce at the end. wred[] reads are 4-address LDS reads (cheap).
__global__ __launch_bounds__(256) void passB_kernel(
        const float* __restrict__ x, const float* __restrict__ part_wsum,
        float* __restrict__ part_pool) {
    __shared__ float wred[3 * NPB];                // 1.5 KB
    __shared__ float red[4][3][HH];                // 3 KB
    const int b  = blockIdx.x / KS;
    const int ks = blockIdx.x % KS;
    const int tid = threadIdx.x;                   // 256 threads

    // reduce slice partials for this node range: wred[g][n]
    for (int i = tid; i < 3 * NPB; i += 256) {
        const int g = i / NPB, n = i % NPB;
        const float* src = part_wsum + (size_t)b * SLICES * (3 * NN)
                         + (size_t)g * NN + (size_t)ks * NPB + n;
        float v = 0.0f;
#pragma unroll
        for (int s = 0; s < SLICES; ++s) v += src[(size_t)s * (3 * NN)];
        wred[i] = v;
    }
    __syncthreads();

    const int w  = tid >> 6;                       // wave 0..3
    const int l  = tid & 63;                       // lane
    const int rg = l >> 4;                         // row-in-group 0..3
    const int hq = l & 15;                         // h quartet 0..15

    float4 a0 = make_float4(0.f, 0.f, 0.f, 0.f);
    float4 a1 = a0, a2 = a0;
#pragma unroll
    for (int it = 0; it < NPB / 16; ++it) {        // 8 iterations
        const int n = it * 16 + w * 4 + rg;        // node within slice
        const float4 xv = ((const float4*)(x +
            ((size_t)b * NN + (size_t)ks * NPB + n) * HH))[hq];
        const float w0 = wred[0 * NPB + n];
        const float w1 = wred[1 * NPB + n];
        const float w2 = wred[2 * NPB + n];
        a0.x += w0 * xv.x; a0.y += w0 * xv.y; a0.z += w0 * xv.z; a0.w += w0 * xv.w;
        a1.x += w1 * xv.x; a1.y += w1 * xv.y; a1.z += w1 * xv.z; a1.w += w1 * xv.w;
        a2.x += w2 * xv.x; a2.y += w2 * xv.y; a2.z += w2 * xv.z; a2.w += w2 * xv.w;
    }

    // reduce across the 4 row-groups (lane bits 4,5) via shuffles
#pragma unroll
    for (int m = 16; m <= 32; m <<= 1) {
        a0.x += __shfl_xor(a0.x, m, 64); a0.y += __shfl_xor(a0.y, m, 64);
        a0.z += __shfl_xor(a0.z, m, 64); a0.w += __shfl_xor(a0.w, m, 64);
        a1.x += __shfl_xor(a1.x, m, 64); a1.y += __shfl_xor(a1.y, m, 64);
        a1.z += __shfl_xor(a1.z, m, 64); a1.w += __shfl_xor(a1.w, m, 64);
        a2.x += __shfl_xor(a2.x, m, 64); a2.y += __shfl_xor(a2.y, m, 64);
        a2.z += __shfl_xor(a2.z, m, 64); a2.w += __shfl_xor(a2.w, m, 64);
    }
    if (rg == 0) {                                 // 16 lanes/wave write
        red[w][0][4 * hq + 0] = a0.x; red[w][0][4 * hq + 1] = a0.y;
        red[w][0][4 * hq + 2] = a0.z; red[w][0][4 * hq + 3] = a0.w;
        red[w][1][4 * hq + 0] = a1.x; red[w][1][4 * hq + 1] = a1.y;
        red[w][1][4 * hq + 2] = a1.z; red[w][1][4 * hq + 3] = a1.w;
        red[w][2][4 * hq + 0] = a2.x; red[w][2][4 * hq + 1] = a2.y;
        red[w][2][4 * hq + 2] = a2.z; red[w][2][4 * hq + 3] = a2.w;
    }
    __syncthreads();

    if (tid < 3 * HH) {
        const int g = tid >> 6, h2 = tid & 63;
        const float v = red[0][g][h2] + red[1][g][h2]
                      + red[2][g][h2] + red[3][g][h2];
        part_pool[(((size_t)b * KS + ks) * 3 + g) * HH + h2] = v;
    }
}

// ---------------- Pass C: tiny 3-token multi-head attention per graph -------
__global__ __launch_bounds__(192) void passC_kernel(
        const float* __restrict__ part_pool,
        const float* __restrict__ Wq, const float* __restrict__ Wk,
        const float* __restrict__ Wv, float* __restrict__ out) {
    __shared__ float p[3][HH];                     // pooled [3][64]
    __shared__ float Wl[3][HH][HH + 1];            // padded
    __shared__ float Ql[3][HH], Kl[3][HH], Vl[3][HH];
    const int b = blockIdx.x;
    const int tid = threadIdx.x;                   // 192
    const int q = tid >> 6, h = tid & 63;

    // reduce pool partials
    float pv = 0.0f;
#pragma unroll
    for (int s = 0; s < KS; ++s)
        pv += part_pool[(((size_t)b * KS + s) * 3 + q) * HH + h];
    p[q][h] = pv;

    // stage the three weight matrices (row-major [h][k], padded)
    for (int i = tid; i < 3 * HH * HH; i += 192) {
        const int m = i >> 12;                     // 4096 elems per matrix
        const int rem = i & 4095;
        const int r = rem >> 6, c = rem & 63;
        const float* Wsrc = (m == 0) ? Wq : (m == 1) ? Wk : Wv;
        Wl[m][r][c] = Wsrc[rem];
    }
    __syncthreads();

    // Q[q][h] = sum_k p[q][k] * W[h][k]   (y = x @ W^T)
    float accq = 0.0f, acck = 0.0f, accv = 0.0f;
#pragma unroll
    for (int k = 0; k < HH; ++k) {
        const float pk = p[q][k];
        accq += pk * Wl[0][h][k];
        acck += pk * Wl[1][h][k];
        accv += pk * Wl[2][h][k];
    }
    Ql[q][h] = accq; Kl[q][h] = acck; Vl[q][h] = accv;
    __syncthreads();

    // scores over 3 keys for this (q, head) ; NORM = 1/sqrt(16) = 0.25
    const int nh = h >> 4;
    float s0 = 0.0f, s1 = 0.0f, s2 = 0.0f;
#pragma unroll
    for (int d = 0; d < DHD; ++d) {
        const float qq = Ql[q][nh * DHD + d];
        s0 += qq * Kl[0][nh * DHD + d];
        s1 += qq * Kl[1][nh * DHD + d];
        s2 += qq * Kl[2][nh * DHD + d];
    }
    s0 *= 0.25f; s1 *= 0.25f; s2 *= 0.25f;
    const float mx = fmaxf(s0, fmaxf(s1, s2));
    const float e0 = expf(s0 - mx), e1 = expf(s1 - mx), e2 = expf(s2 - mx);
    const float inv = 1.0f / (e0 + e1 + e2);
    const float av = (e0 * Vl[0][h] + e1 * Vl[1][h] + e2 * Vl[2][h]) * inv;

    out[(size_t)b * (3 * HH) + (size_t)q * HH + h] = av;
}

extern "C" void kernel_launch(void* const* d_in, const int* in_sizes, int n_in,
                              void* d_out, int out_size, void* d_ws, size_t ws_size,
                              hipStream_t stream) {
    const float* x      = (const float*)d_in[0];
    // d_in[1] = batch (unused; fixed N nodes/graph), d_in[2] = batch_size (fixed 64)
    const int*   d_rows = (const int*)d_in[3];
    const int*   d_cols = (const int*)d_in[4];
    const float* d_vals = (const float*)d_in[5];
    const int*   d_index= (const int*)d_in[6];
    const float* Wq     = (const float*)d_in[7];
    const float* Wk     = (const float*)d_in[8];
    const float* Wv     = (const float*)d_in[9];
    float* out = (float*)d_out;

    // workspace layout (all fully written before read; no zeroing needed):
    //   part_wsum: B*SLICES*3*N floats = 6.29 MB
    //   part_pool: B*KS*3*H floats     = 0.79 MB
    float* part_wsum = (float*)d_ws;
    float* part_pool = part_wsum + (size_t)BG * SLICES * 3 * NN;

    passA_kernel<<<BG * SLICES, 512, 0, stream>>>(d_rows, d_cols, d_vals,
                                                  d_index, part_wsum);
    passB_kernel<<<BG * KS, 256, 0, stream>>>(x, part_wsum, part_pool);
    passC_kernel<<<BG, 192, 0, stream>>>(part_pool, Wq, Wk, Wv, out);
}

// Round 9
// 134.656 us; speedup vs baseline: 1.9698x; 1.0089x over previous
//
#include <hip/hip_runtime.h>
#include <math.h>

// Problem constants (fixed by the reference)
#define BG 64            // graphs
#define NN 2048          // nodes per graph
#define HH 64            // hidden dim
#define NHD 4            // heads
#define DHD 16           // head dim
#define MM (3*NN)        // 6144 framelet rows
#define EE (8*MM)        // 49152 nnz per graph
#define SLICES 4         // E-slices per graph (pass A)
#define EPB (EE/SLICES)  // 12288 entries per pass-A block
#define KS 16            // node-split blocks per graph (pass B)
#define NPB (NN/KS)      // 128 nodes per pass-B block

// ---------------- Pass A: wsum[b][g][n] = sum of vals with col n, group g ----
// 256 blocks x 1024 threads (48 KB LDS, 16 waves/CU). The inner loop is a
// dependent chain (global int4 load -> LDS gidx gather -> LDS atomic), so the
// kernel is latency-bound: 16 waves/CU doubles latency hiding vs 512 threads.
__global__ __launch_bounds__(1024) void passA_kernel(
        const int* __restrict__ d_rows, const int* __restrict__ d_cols,
        const float* __restrict__ d_vals, const int* __restrict__ d_index,
        float* __restrict__ part_wsum) {
    __shared__ float w[3 * NN];                    // 24 KB
    __shared__ int   gidx[MM];                     // 24 KB (row -> group)
    const int b = blockIdx.x / SLICES;
    const int s = blockIdx.x % SLICES;
    const int tid = threadIdx.x;

    const int4* di4 = (const int4*)(d_index + (size_t)b * MM);
    for (int i = tid; i < MM / 4; i += 1024) ((int4*)gidx)[i] = di4[i];
    float4* w4 = (float4*)w;
    const float4 z4 = make_float4(0.f, 0.f, 0.f, 0.f);
    for (int i = tid; i < 3 * NN / 4; i += 1024) w4[i] = z4;
    __syncthreads();

    const size_t base = (size_t)b * EE + (size_t)s * EPB;   // 16B-aligned
    const int4*   rows4 = (const int4*)(d_rows + base);
    const int4*   cols4 = (const int4*)(d_cols + base);
    const float4* vals4 = (const float4*)(d_vals + base);

#pragma unroll
    for (int it = 0; it < EPB / 4 / 1024; ++it) {  // 3 iterations
        const int idx = it * 1024 + tid;
        int4   r = rows4[idx];
        int4   c = cols4[idx];
        float4 v = vals4[idx];
        int g0 = gidx[r.x], g1 = gidx[r.y], g2 = gidx[r.z], g3 = gidx[r.w];
        atomicAdd(&w[g0 * NN + c.x], v.x);
        atomicAdd(&w[g1 * NN + c.y], v.y);
        atomicAdd(&w[g2 * NN + c.z], v.z);
        atomicAdd(&w[g3 * NN + c.w], v.w);
    }
    __syncthreads();

    float4* out4 = (float4*)(part_wsum + ((size_t)b * SLICES + s) * (3 * NN));
    for (int i = tid; i < 3 * NN / 4; i += 1024) out4[i] = w4[i];
}

// ---------------- Pass B: part_pool[b][ks][g][h] = wred[g][n] @ x[b][n][h] --
// 1024 blocks x 256 threads (4 blocks/CU -> 16 waves/CU). Each lane loads a
// float4 of x (wave covers 4 rows = 1 KB per load instruction); per-thread
// acc[3 groups][4 h]; row-group reduce via shfl_xor(16/32); cross-wave LDS
// reduce at the end. wred[] reads are 4-address LDS reads (cheap).
__global__ __launch_bounds__(256) void passB_kernel(
        const float* __restrict__ x, const float* __restrict__ part_wsum,
        float* __restrict__ part_pool) {
    __shared__ float wred[3 * NPB];                // 1.5 KB
    __shared__ float red[4][3][HH];                // 3 KB
    const int b  = blockIdx.x / KS;
    const int ks = blockIdx.x % KS;
    const int tid = threadIdx.x;                   // 256 threads

    // reduce slice partials for this node range: wred[g][n]
    for (int i = tid; i < 3 * NPB; i += 256) {
        const int g = i / NPB, n = i % NPB;
        const float* src = part_wsum + (size_t)b * SLICES * (3 * NN)
                         + (size_t)g * NN + (size_t)ks * NPB + n;
        float v = 0.0f;
#pragma unroll
        for (int s = 0; s < SLICES; ++s) v += src[(size_t)s * (3 * NN)];
        wred[i] = v;
    }
    __syncthreads();

    const int w  = tid >> 6;                       // wave 0..3
    const int l  = tid & 63;                       // lane
    const int rg = l >> 4;                         // row-in-group 0..3
    const int hq = l & 15;                         // h quartet 0..15

    float4 a0 = make_float4(0.f, 0.f, 0.f, 0.f);
    float4 a1 = a0, a2 = a0;
#pragma unroll
    for (int it = 0; it < NPB / 16; ++it) {        // 8 iterations
        const int n = it * 16 + w * 4 + rg;        // node within slice
        const float4 xv = ((const float4*)(x +
            ((size_t)b * NN + (size_t)ks * NPB + n) * HH))[hq];
        const float w0 = wred[0 * NPB + n];
        const float w1 = wred[1 * NPB + n];
        const float w2 = wred[2 * NPB + n];
        a0.x += w0 * xv.x; a0.y += w0 * xv.y; a0.z += w0 * xv.z; a0.w += w0 * xv.w;
        a1.x += w1 * xv.x; a1.y += w1 * xv.y; a1.z += w1 * xv.z; a1.w += w1 * xv.w;
        a2.x += w2 * xv.x; a2.y += w2 * xv.y; a2.z += w2 * xv.z; a2.w += w2 * xv.w;
    }

    // reduce across the 4 row-groups (lane bits 4,5) via shuffles
#pragma unroll
    for (int m = 16; m <= 32; m <<= 1) {
        a0.x += __shfl_xor(a0.x, m, 64); a0.y += __shfl_xor(a0.y, m, 64);
        a0.z += __shfl_xor(a0.z, m, 64); a0.w += __shfl_xor(a0.w, m, 64);
        a1.x += __shfl_xor(a1.x, m, 64); a1.y += __shfl_xor(a1.y, m, 64);
        a1.z += __shfl_xor(a1.z, m, 64); a1.w += __shfl_xor(a1.w, m, 64);
        a2.x += __shfl_xor(a2.x, m, 64); a2.y += __shfl_xor(a2.y, m, 64);
        a2.z += __shfl_xor(a2.z, m, 64); a2.w += __shfl_xor(a2.w, m, 64);
    }
    if (rg == 0) {                                 // 16 lanes/wave write
        red[w][0][4 * hq + 0] = a0.x; red[w][0][4 * hq + 1] = a0.y;
        red[w][0][4 * hq + 2] = a0.z; red[w][0][4 * hq + 3] = a0.w;
        red[w][1][4 * hq + 0] = a1.x; red[w][1][4 * hq + 1] = a1.y;
        red[w][1][4 * hq + 2] = a1.z; red[w][1][4 * hq + 3] = a1.w;
        red[w][2][4 * hq + 0] = a2.x; red[w][2][4 * hq + 1] = a2.y;
        red[w][2][4 * hq + 2] = a2.z; red[w][2][4 * hq + 3] = a2.w;
    }
    __syncthreads();

    if (tid < 3 * HH) {
        const int g = tid >> 6, h2 = tid & 63;
        const float v = red[0][g][h2] + red[1][g][h2]
                      + red[2][g][h2] + red[3][g][h2];
        part_pool[(((size_t)b * KS + ks) * 3 + g) * HH + h2] = v;
    }
}

// ---------------- Pass C: tiny 3-token multi-head attention per graph -------
__global__ __launch_bounds__(192) void passC_kernel(
        const float* __restrict__ part_pool,
        const float* __restrict__ Wq, const float* __restrict__ Wk,
        const float* __restrict__ Wv, float* __restrict__ out) {
    __shared__ float p[3][HH];                     // pooled [3][64]
    __shared__ float Wl[3][HH][HH + 1];            // padded
    __shared__ float Ql[3][HH], Kl[3][HH], Vl[3][HH];
    const int b = blockIdx.x;
    const int tid = threadIdx.x;                   // 192
    const int q = tid >> 6, h = tid & 63;

    // reduce pool partials
    float pv = 0.0f;
#pragma unroll
    for (int s = 0; s < KS; ++s)
        pv += part_pool[(((size_t)b * KS + s) * 3 + q) * HH + h];
    p[q][h] = pv;

    // stage the three weight matrices (row-major [h][k], padded)
    for (int i = tid; i < 3 * HH * HH; i += 192) {
        const int m = i >> 12;                     // 4096 elems per matrix
        const int rem = i & 4095;
        const int r = rem >> 6, c = rem & 63;
        const float* Wsrc = (m == 0) ? Wq : (m == 1) ? Wk : Wv;
        Wl[m][r][c] = Wsrc[rem];
    }
    __syncthreads();

    // Q[q][h] = sum_k p[q][k] * W[h][k]   (y = x @ W^T)
    float accq = 0.0f, acck = 0.0f, accv = 0.0f;
#pragma unroll
    for (int k = 0; k < HH; ++k) {
        const float pk = p[q][k];
        accq += pk * Wl[0][h][k];
        acck += pk * Wl[1][h][k];
        accv += pk * Wl[2][h][k];
    }
    Ql[q][h] = accq; Kl[q][h] = acck; Vl[q][h] = accv;
    __syncthreads();

    // scores over 3 keys for this (q, head) ; NORM = 1/sqrt(16) = 0.25
    const int nh = h >> 4;
    float s0 = 0.0f, s1 = 0.0f, s2 = 0.0f;
#pragma unroll
    for (int d = 0; d < DHD; ++d) {
        const float qq = Ql[q][nh * DHD + d];
        s0 += qq * Kl[0][nh * DHD + d];
        s1 += qq * Kl[1][nh * DHD + d];
        s2 += qq * Kl[2][nh * DHD + d];
    }
    s0 *= 0.25f; s1 *= 0.25f; s2 *= 0.25f;
    const float mx = fmaxf(s0, fmaxf(s1, s2));
    const float e0 = expf(s0 - mx), e1 = expf(s1 - mx), e2 = expf(s2 - mx);
    const float inv = 1.0f / (e0 + e1 + e2);
    const float av = (e0 * Vl[0][h] + e1 * Vl[1][h] + e2 * Vl[2][h]) * inv;

    out[(size_t)b * (3 * HH) + (size_t)q * HH + h] = av;
}

extern "C" void kernel_launch(void* const* d_in, const int* in_sizes, int n_in,
                              void* d_out, int out_size, void* d_ws, size_t ws_size,
                              hipStream_t stream) {
    const float* x      = (const float*)d_in[0];
    // d_in[1] = batch (unused; fixed N nodes/graph), d_in[2] = batch_size (fixed 64)
    const int*   d_rows = (const int*)d_in[3];
    const int*   d_cols = (const int*)d_in[4];
    const float* d_vals = (const float*)d_in[5];
    const int*   d_index= (const int*)d_in[6];
    const float* Wq     = (const float*)d_in[7];
    const float* Wk     = (const float*)d_in[8];
    const float* Wv     = (const float*)d_in[9];
    float* out = (float*)d_out;

    // workspace layout (all fully written before read; no zeroing needed):
    //   part_wsum: B*SLICES*3*N floats = 6.29 MB
    //   part_pool: B*KS*3*H floats     = 0.79 MB
    float* part_wsum = (float*)d_ws;
    float* part_pool = part_wsum + (size_t)BG * SLICES * 3 * NN;

    passA_kernel<<<BG * SLICES, 1024, 0, stream>>>(d_rows, d_cols, d_vals,
                                                   d_index, part_wsum);
    passB_kernel<<<BG * KS, 256, 0, stream>>>(x, part_wsum, part_pool);
    passC_kernel<<<BG, 192, 0, stream>>>(part_pool, Wq, Wk, Wv, out);
}